// Round 1
// baseline (86.159 us; speedup 1.0000x reference)
//
#include <hip/hip_runtime.h>
#include <stdint.h>

#define W_ 512
#define H_ 512
#define HW_ (512 * 512)

// ---- projection: exact replica of the reference f32 arithmetic ----
// xf = x/(z+1e-6)*512 + 256 ; clip ±1e9 ; trunc toward zero ; bounds test
__device__ __forceinline__ int project_pix(float x, float y, float z) {
    float zz = z + 1e-6f;
    float xf = x / zz * 512.0f + 256.0f;
    float yf = y / zz * 512.0f + 256.0f;
    xf = fminf(fmaxf(xf, -1e9f), 1e9f);
    yf = fminf(fmaxf(yf, -1e9f), 1e9f);
    int xi = (int)xf;   // trunc toward zero, fits int32 after clip
    int yi = (int)yf;
    if (xi >= 0 && xi < W_ && yi >= 0 && yi < H_) return yi * W_ + xi;
    return -1;
}

// ---- pass 1: per-pixel counts ----
__global__ void k_count(const float* __restrict__ xyz, unsigned int* __restrict__ cnt,
                        int N, int total) {
    int g = blockIdx.x * blockDim.x + threadIdx.x;
    if (g >= total) return;
    float x = xyz[3 * (size_t)g + 0];
    float y = xyz[3 * (size_t)g + 1];
    float z = xyz[3 * (size_t)g + 2];
    int pix = project_pix(x, y, z);
    if (pix >= 0) {
        int b = g / N;
        atomicAdd(&cnt[(size_t)b * HW_ + pix], 1u);
    }
}

// ---- exclusive scan over nb elements: 2048 per block ----
#define SCAN_B 256
#define SCAN_I 8
#define SCAN_TILE (SCAN_B * SCAN_I)

__global__ void k_scanA(const unsigned int* __restrict__ cnt, unsigned int* __restrict__ off,
                        unsigned int* __restrict__ sums, int n) {
    __shared__ unsigned int sm[SCAN_B];
    int base = blockIdx.x * SCAN_TILE + threadIdx.x * SCAN_I;
    unsigned int it[SCAN_I];
    unsigned int tot = 0;
#pragma unroll
    for (int i = 0; i < SCAN_I; ++i) {
        int ix = base + i;
        it[i] = (ix < n) ? cnt[ix] : 0u;
        tot += it[i];
    }
    sm[threadIdx.x] = tot;
    __syncthreads();
    for (int d = 1; d < SCAN_B; d <<= 1) {
        unsigned int v = (threadIdx.x >= (unsigned)d) ? sm[threadIdx.x - d] : 0u;
        __syncthreads();
        sm[threadIdx.x] += v;
        __syncthreads();
    }
    unsigned int incl = sm[threadIdx.x];
    unsigned int excl = incl - tot;
    if (threadIdx.x == SCAN_B - 1) sums[blockIdx.x] = incl;
    unsigned int run = excl;
#pragma unroll
    for (int i = 0; i < SCAN_I; ++i) {
        int ix = base + i;
        if (ix < n) off[ix] = run;
        run += it[i];
    }
}

__global__ void k_scanB(unsigned int* __restrict__ sums, int n) {
    __shared__ unsigned int sm[1024];
    int t = threadIdx.x;
    unsigned int v = (t < n) ? sums[t] : 0u;
    sm[t] = v;
    __syncthreads();
    for (int d = 1; d < 1024; d <<= 1) {
        unsigned int u = (t >= d) ? sm[t - d] : 0u;
        __syncthreads();
        sm[t] += u;
        __syncthreads();
    }
    if (t < n) sums[t] = sm[t] - v;  // exclusive
}

__global__ void k_scanC(unsigned int* __restrict__ off, const unsigned int* __restrict__ sums,
                        int n) {
    int i = blockIdx.x * blockDim.x + threadIdx.x;
    if (i < n) off[i] += sums[i / SCAN_TILE];
}

// ---- pass 2: scatter gaussian indices into bins (mutates off -> end offsets) ----
__global__ void k_scatter(const float* __restrict__ xyz, unsigned int* __restrict__ off,
                          unsigned int* __restrict__ idxb, int N, int total) {
    int g = blockIdx.x * blockDim.x + threadIdx.x;
    if (g >= total) return;
    float x = xyz[3 * (size_t)g + 0];
    float y = xyz[3 * (size_t)g + 1];
    float z = xyz[3 * (size_t)g + 2];
    int pix = project_pix(x, y, z);
    if (pix >= 0) {
        int b = g / N;
        unsigned int pos = atomicAdd(&off[(size_t)b * HW_ + pix], 1u);
        idxb[pos] = (unsigned int)(g - b * N);  // index within batch
    }
}

// ---- pass 3: per-pixel ordered composite (z descending, ties by index asc) ----
__global__ void k_composite(const float* __restrict__ xyz, const float* __restrict__ opacity,
                            const float* __restrict__ color, const unsigned int* __restrict__ cnt,
                            const unsigned int* __restrict__ off, const unsigned int* __restrict__ idxb,
                            float* __restrict__ out, int N, int B) {
    int p = blockIdx.x * blockDim.x + threadIdx.x;
    int nb = B * HW_;
    if (p >= nb) return;
    int b = p / HW_;
    int pl = p - b * HW_;

    int k = (int)cnt[p];
    float r = 0.f, g2 = 0.f, bl = 0.f, depth = 0.f, T = 1.f;
    if (k > 0) {
        int base = (int)off[p] - k;  // off was bumped to end by scatter
        const float* X = xyz + (size_t)b * N * 3;
        const float* O = opacity + (size_t)b * N;
        const float* C = color + (size_t)b * N * 3;
        float prev_z = __builtin_inff();
        int prev_i = -1;
        for (int s = 0; s < k; ++s) {
            // select next in order (z desc, idx asc), strictly after (prev_z, prev_i)
            float best_z = -__builtin_inff();
            int best_i = 0x7fffffff;
            for (int t = 0; t < k; ++t) {
                int n = (int)idxb[base + t];
                float z = X[3 * (size_t)n + 2];
                bool after = (z < prev_z) || (z == prev_z && n > prev_i);
                bool better = (z > best_z) || (z == best_z && n < best_i);
                if (after && better) { best_z = z; best_i = n; }
            }
            float o = O[best_i];
            float a = o * T;
            const float* c = C + 3 * (size_t)best_i;
            r  += a * c[0];
            g2 += a * c[1];
            bl += a * c[2];
            T *= (1.0f - o);
            depth = best_z;  // last composited = min z = front-most
            prev_z = best_z;
            prev_i = best_i;
        }
    }
    size_t HWs = (size_t)HW_;
    out[((size_t)b * 3 + 0) * HWs + pl] = r;
    out[((size_t)b * 3 + 1) * HWs + pl] = g2;
    out[((size_t)b * 3 + 2) * HWs + pl] = bl;
    out[(size_t)B * 3 * HWs + (size_t)b * HWs + pl] = depth;
}

extern "C" void kernel_launch(void* const* d_in, const int* in_sizes, int n_in,
                              void* d_out, int out_size, void* d_ws, size_t ws_size,
                              hipStream_t stream) {
    const float* xyz     = (const float*)d_in[0];
    // d_in[1] = scale (unused), d_in[2] = rotation (unused)
    const float* opacity = (const float*)d_in[3];
    const float* color   = (const float*)d_in[4];
    float* out = (float*)d_out;

    int B = out_size / (4 * HW_);        // render (B,3,H,W) + depth (B,1,H,W)
    int N = in_sizes[0] / (3 * B);
    int total = B * N;
    int nb = B * HW_;

    unsigned int* cnt  = (unsigned int*)d_ws;
    unsigned int* off  = cnt + nb;
    unsigned int* idxb = off + nb;
    unsigned int* sums = idxb + total;

    hipMemsetAsync(cnt, 0, (size_t)nb * sizeof(unsigned int), stream);

    int blk = 256;
    k_count<<<(total + blk - 1) / blk, blk, 0, stream>>>(xyz, cnt, N, total);

    int nblocks = (nb + SCAN_TILE - 1) / SCAN_TILE;  // 1024 for B=8
    k_scanA<<<nblocks, SCAN_B, 0, stream>>>(cnt, off, sums, nb);
    k_scanB<<<1, 1024, 0, stream>>>(sums, nblocks);
    k_scanC<<<(nb + blk - 1) / blk, blk, 0, stream>>>(off, sums, nb);

    k_scatter<<<(total + blk - 1) / blk, blk, 0, stream>>>(xyz, off, idxb, N, total);

    k_composite<<<(nb + blk - 1) / blk, blk, 0, stream>>>(xyz, opacity, color, cnt, off, idxb,
                                                          out, N, B);
}

// Round 2
// 54.585 us; speedup vs baseline: 1.5784x; 1.5784x over previous
//
#include <hip/hip_runtime.h>
#include <stdint.h>

#define W_ 512
#define H_ 512
#define HW_ (512 * 512)
#define KMAX 32

// ---- projection: exact replica of the reference f32 arithmetic ----
// xf = x/(z+1e-6)*512 + 256 ; clip ±1e9 ; trunc toward zero ; bounds test
__device__ __forceinline__ int project_pix(float x, float y, float z) {
    float zz = z + 1e-6f;
    float xf = x / zz * 512.0f + 256.0f;
    float yf = y / zz * 512.0f + 256.0f;
    xf = fminf(fmaxf(xf, -1e9f), 1e9f);
    yf = fminf(fmaxf(yf, -1e9f), 1e9f);
    int xi = (int)xf;   // trunc toward zero, fits int32 after clip
    int yi = (int)yf;
    if (xi >= 0 && xi < W_ && yi >= 0 && yi < H_) return yi * W_ + xi;
    return -1;
}

// ---- pass 0: head[] = ~0u, vectorized ----
__global__ void __launch_bounds__(256) k_init(uint4* __restrict__ head4, int n4) {
    int i = blockIdx.x * blockDim.x + threadIdx.x;
    if (i < n4) head4[i] = make_uint4(~0u, ~0u, ~0u, ~0u);
}

// ---- pass 1: build per-pixel linked lists (global gaussian index as node id) ----
__global__ void __launch_bounds__(256) k_build(const float* __restrict__ xyz,
                                               unsigned int* __restrict__ head,
                                               unsigned int* __restrict__ nxt,
                                               int N, int total) {
    int g = blockIdx.x * blockDim.x + threadIdx.x;
    if (g >= total) return;
    float x = xyz[3 * (size_t)g + 0];
    float y = xyz[3 * (size_t)g + 1];
    float z = xyz[3 * (size_t)g + 2];
    int pix = project_pix(x, y, z);
    if (pix >= 0) {
        int b = g / N;
        unsigned int old = atomicExch(&head[(size_t)b * HW_ + pix], (unsigned int)g);
        nxt[g] = old;
    }
}

// ---- pass 2: per-pixel ordered composite (z descending, ties by index asc) ----
__global__ void __launch_bounds__(256) k_composite(const float* __restrict__ xyz,
                                                   const float* __restrict__ opacity,
                                                   const float* __restrict__ color,
                                                   const unsigned int* __restrict__ head,
                                                   const unsigned int* __restrict__ nxt,
                                                   float* __restrict__ out, int B) {
    int p = blockIdx.x * blockDim.x + threadIdx.x;
    int nb = B * HW_;
    if (p >= nb) return;
    int b = p / HW_;
    int pl = p - b * HW_;

    float r = 0.f, g2 = 0.f, bl = 0.f, depth = 0.f, T = 1.f;

    unsigned int h = head[p];
    if (h != ~0u) {
        // collect chain into local list (z, global idx)
        float zs[KMAX];
        int   is_[KMAX];
        int k = 0;
        unsigned int n = h;
        while (n != ~0u) {
            if (k < KMAX) {
                zs[k]  = xyz[3 * (size_t)n + 2];
                is_[k] = (int)n;
            }
            ++k;
            n = nxt[n];
        }

        float prev_z = __builtin_inff();
        int prev_i = -1;
        if (k <= KMAX) {
            // fast path: selection over local arrays
            for (int s = 0; s < k; ++s) {
                float best_z = -__builtin_inff();
                int best_i = 0x7fffffff;
                for (int t = 0; t < k; ++t) {
                    float z = zs[t];
                    int   i = is_[t];
                    bool after  = (z < prev_z) || (z == prev_z && i > prev_i);
                    bool better = (z > best_z) || (z == best_z && i < best_i);
                    if (after && better) { best_z = z; best_i = i; }
                }
                float o = opacity[best_i];
                float a = o * T;
                const float* c = color + 3 * (size_t)best_i;
                r  += a * c[0];
                g2 += a * c[1];
                bl += a * c[2];
                T *= (1.0f - o);
                depth = best_z;
                prev_z = best_z;
                prev_i = best_i;
            }
        } else {
            // overflow fallback (vanishingly rare): selection by re-walking the list
            for (int s = 0; s < k; ++s) {
                float best_z = -__builtin_inff();
                int best_i = 0x7fffffff;
                unsigned int m = h;
                while (m != ~0u) {
                    float z = xyz[3 * (size_t)m + 2];
                    int   i = (int)m;
                    bool after  = (z < prev_z) || (z == prev_z && i > prev_i);
                    bool better = (z > best_z) || (z == best_z && i < best_i);
                    if (after && better) { best_z = z; best_i = i; }
                    m = nxt[m];
                }
                float o = opacity[best_i];
                float a = o * T;
                const float* c = color + 3 * (size_t)best_i;
                r  += a * c[0];
                g2 += a * c[1];
                bl += a * c[2];
                T *= (1.0f - o);
                depth = best_z;
                prev_z = best_z;
                prev_i = best_i;
            }
        }
    }

    size_t HWs = (size_t)HW_;
    out[((size_t)b * 3 + 0) * HWs + pl] = r;
    out[((size_t)b * 3 + 1) * HWs + pl] = g2;
    out[((size_t)b * 3 + 2) * HWs + pl] = bl;
    out[(size_t)B * 3 * HWs + (size_t)b * HWs + pl] = depth;
}

extern "C" void kernel_launch(void* const* d_in, const int* in_sizes, int n_in,
                              void* d_out, int out_size, void* d_ws, size_t ws_size,
                              hipStream_t stream) {
    const float* xyz     = (const float*)d_in[0];
    // d_in[1] = scale (unused), d_in[2] = rotation (unused)
    const float* opacity = (const float*)d_in[3];
    const float* color   = (const float*)d_in[4];
    float* out = (float*)d_out;

    int B = out_size / (4 * HW_);        // render (B,3,H,W) + depth (B,1,H,W)
    int N = in_sizes[0] / (3 * B);
    int total = B * N;                   // note: composite uses GLOBAL index; opacity/color
    int nb = B * HW_;                    // indexed globally since arrays are (B,N,*) flat

    unsigned int* head = (unsigned int*)d_ws;          // nb u32
    unsigned int* nxt  = head + nb;                    // total u32

    int blk = 256;
    int n4 = nb / 4;                     // nb = B*512*512, divisible by 4
    k_init<<<(n4 + blk - 1) / blk, blk, 0, stream>>>((uint4*)head, n4);

    k_build<<<(total + blk - 1) / blk, blk, 0, stream>>>(xyz, head, nxt, N, total);

    k_composite<<<(nb + blk - 1) / blk, blk, 0, stream>>>(xyz, opacity, color, head, nxt,
                                                          out, B);
}